// Round 1
// baseline (4463.594 us; speedup 1.0000x reference)
//
#include <hip/hip_runtime.h>
#include <hip/hip_bf16.h>

#define BATCH   8
#define C_DIM   512
#define HWD     56
#define NPIX    3136   // 56*56
#define PW      14
#define PP      196    // 14*14
#define M_TOT   588    // 3*196
#define BM_ROWS 4704   // 8*588
#define HEADS   8
#define HD      64
#define N_SEQ   3136
#define SM_SCALE 0.125f

// ---------------------------------------------------------------------------
// Kernel A: the three depthwise branches. One block per (b,c) plane.
// Writes l_pre in [B, C, M] layout (coalesced 588-float runs per block).
// ---------------------------------------------------------------------------
__global__ __launch_bounds__(256) void k_branches(
    const float* __restrict__ x,
    const float* __restrict__ w1a, const float* __restrict__ b1a,
    const float* __restrict__ w1b, const float* __restrict__ b1b,
    const float* __restrict__ w2,  const float* __restrict__ b2,
    const float* __restrict__ w3,  const float* __restrict__ b3,
    float* __restrict__ l_pre)
{
    __shared__ float xs[NPIX];
    __shared__ float y1s[HWD * PW];   // 56x14 after (1,4) conv
    __shared__ float pools[PP];
    const int c = blockIdx.x, b = blockIdx.y, tid = threadIdx.x;
    const float* xp = x + ((size_t)(b * C_DIM + c)) * NPIX;
    for (int i = tid; i < NPIX / 4; i += 256)
        ((float4*)xs)[i] = ((const float4*)xp)[i];
    __syncthreads();

    const float wa0 = w1a[c*4+0], wa1 = w1a[c*4+1], wa2 = w1a[c*4+2], wa3 = w1a[c*4+3];
    const float ba = b1a[c];
    for (int i = tid; i < HWD * PW; i += 256) {
        int h = i / PW, w = i % PW;
        const float* r = xs + h * HWD + w * 4;
        float v = ba + r[0]*wa0 + r[1]*wa1 + r[2]*wa2 + r[3]*wa3;
        y1s[i] = fmaxf(v, 0.f);
    }
    if (tid < PP) {
        int h = tid / PW, w = tid % PW;
        float s = 0.f;
        #pragma unroll
        for (int r = 0; r < 4; ++r) {
            const float* rr = xs + (h*4 + r) * HWD + w * 4;
            s += rr[0] + rr[1] + rr[2] + rr[3];
        }
        pools[tid] = s * (1.f / 16.f);
    }
    __syncthreads();

    if (tid < PP) {
        int h = tid / PW, w = tid % PW;
        float* lp = l_pre + ((size_t)(b * C_DIM + c)) * M_TOT;
        // branch 1: second conv (4,1) stride (4,1) over y1s
        float v1 = b1b[c];
        v1 += y1s[(h*4+0)*PW + w] * w1b[c*4+0];
        v1 += y1s[(h*4+1)*PW + w] * w1b[c*4+1];
        v1 += y1s[(h*4+2)*PW + w] * w1b[c*4+2];
        v1 += y1s[(h*4+3)*PW + w] * w1b[c*4+3];
        lp[tid] = fmaxf(v1, 0.f);
        // branch 2: 4x4 stride-4 conv
        float v2 = b2[c];
        #pragma unroll
        for (int r = 0; r < 4; ++r)
            #pragma unroll
            for (int s2 = 0; s2 < 4; ++s2)
                v2 += xs[(h*4+r)*HWD + w*4 + s2] * w2[c*16 + r*4 + s2];
        lp[PP + tid] = fmaxf(v2, 0.f);
        // branch 3: 3x3 pad-1 conv over pooled plane
        float v3 = b3[c];
        #pragma unroll
        for (int dh = -1; dh <= 1; ++dh)
            #pragma unroll
            for (int dw = -1; dw <= 1; ++dw) {
                int hh = h + dh, ww = w + dw;
                if (hh >= 0 && hh < PW && ww >= 0 && ww < PW)
                    v3 += pools[hh*PW + ww] * w3[c*9 + (dh+1)*3 + (dw+1)];
            }
        lp[2*PP + tid] = fmaxf(v3, 0.f);
    }
}

// ---------------------------------------------------------------------------
// Kernel B: LayerNorm stats over C for each (b,m). l_pre is [B,C,M].
// Block = (b, m-tile of 64). Thread (cg, ml): cg = tid>>6 sums 128 channels.
// ---------------------------------------------------------------------------
__global__ __launch_bounds__(256) void k_stats(
    const float* __restrict__ l_pre, float2* __restrict__ stats)
{
    __shared__ float ssum[4][64];
    __shared__ float ssq[4][64];
    const int tid = threadIdx.x;
    const int ml = tid & 63, cg = tid >> 6;
    const int b = blockIdx.y;
    const int m = blockIdx.x * 64 + ml;
    float s = 0.f, q = 0.f;
    if (m < M_TOT) {
        const float* base = l_pre + ((size_t)b * C_DIM + cg * 128) * M_TOT + m;
        for (int c = 0; c < 128; ++c) {
            float v = base[(size_t)c * M_TOT];
            s += v; q += v * v;
        }
    }
    ssum[cg][ml] = s; ssq[cg][ml] = q;
    __syncthreads();
    if (tid < 64 && blockIdx.x * 64 + tid < M_TOT) {
        float ts = ssum[0][tid] + ssum[1][tid] + ssum[2][tid] + ssum[3][tid];
        float tq = ssq[0][tid] + ssq[1][tid] + ssq[2][tid] + ssq[3][tid];
        float mu = ts * (1.f / 512.f);
        float var = tq * (1.f / 512.f) - mu * mu;
        stats[(size_t)b * M_TOT + blockIdx.x * 64 + tid] =
            make_float2(mu, rsqrtf(var + 1e-5f));
    }
}

// ---------------------------------------------------------------------------
// Kernel C: kv = LN(l_) @ Wkv^T + bkv, LN fused into A-tile load.
// A rows = (b,m) [4704], cols = c [512]; B = Wkv [1024 x 512].
// K written bf16 [B,h,M,d]; V written fp32 [B,h,M,d].
// ---------------------------------------------------------------------------
__global__ __launch_bounds__(256) void k_kvgemm(
    const float* __restrict__ l_pre, const float2* __restrict__ stats,
    const float* __restrict__ Wkv, const float* __restrict__ bkv,
    const float* __restrict__ gamma, const float* __restrict__ beta,
    __hip_bfloat16* __restrict__ Kb, float* __restrict__ Vf)
{
    __shared__ float As[16][68];
    __shared__ float Bs[16][68];
    const int tid = threadIdx.x;
    const int tx = tid & 15, ty = tid >> 4;
    const int row0 = blockIdx.x * 64, col0 = blockIdx.y * 64;
    // A-load mapping: ln = row within tile, lk = k sub-index
    const int lk = tid >> 6, ln = tid & 63;
    const int grow = row0 + ln;
    const bool rv = (grow < BM_ROWS);
    int b_r = 0, m_r = 0; float mu = 0.f, rstd = 0.f;
    if (rv) {
        b_r = grow / M_TOT; m_r = grow - b_r * M_TOT;
        float2 st = stats[grow];
        mu = st.x; rstd = st.y;
    }
    // B-load mapping
    const int lrow = tid >> 2, lq = tid & 3;
    float acc[4][4] = {};
    for (int c0 = 0; c0 < 512; c0 += 16) {
        __syncthreads();
        #pragma unroll
        for (int l = 0; l < 4; ++l) {
            int k = l * 4 + lk;
            float v = 0.f;
            if (rv) {
                float raw = l_pre[((size_t)(b_r * C_DIM + c0 + k)) * M_TOT + m_r];
                v = (raw - mu) * rstd * gamma[c0 + k] + beta[c0 + k];
            }
            As[k][ln] = v;
        }
        {
            float4 v = *(const float4*)&Wkv[(size_t)(col0 + lrow) * 512 + c0 + lq * 4];
            Bs[lq*4+0][lrow] = v.x; Bs[lq*4+1][lrow] = v.y;
            Bs[lq*4+2][lrow] = v.z; Bs[lq*4+3][lrow] = v.w;
        }
        __syncthreads();
        #pragma unroll
        for (int k = 0; k < 16; ++k) {
            float4 av = *(const float4*)&As[k][ty * 4];
            float4 bv = *(const float4*)&Bs[k][tx * 4];
            float a[4] = {av.x, av.y, av.z, av.w};
            float bb[4] = {bv.x, bv.y, bv.z, bv.w};
            #pragma unroll
            for (int i = 0; i < 4; ++i)
                #pragma unroll
                for (int j = 0; j < 4; ++j)
                    acc[i][j] += a[i] * bb[j];
        }
    }
    #pragma unroll
    for (int i = 0; i < 4; ++i) {
        int r = row0 + ty * 4 + i;
        if (r >= BM_ROWS) break;
        int bb_ = r / M_TOT, m = r - bb_ * M_TOT;
        #pragma unroll
        for (int j = 0; j < 4; ++j) {
            int jg = col0 + tx * 4 + j;
            float val = acc[i][j] + bkv[jg];
            if (jg < 512) {
                int h = jg >> 6, d = jg & 63;
                Kb[(((size_t)(bb_ * HEADS + h)) * M_TOT + m) * HD + d] = __float2bfloat16(val);
            } else {
                int jj = jg - 512; int h = jj >> 6, d = jj & 63;
                Vf[(((size_t)(bb_ * HEADS + h)) * M_TOT + m) * HD + d] = val;
            }
        }
    }
}

// ---------------------------------------------------------------------------
// Kernel D: q = x_layer @ Wq^T + bq. x stored [B,C,N] (already the transposed
// layout the LDS tile wants -> fully coalesced). Q written bf16 [B,h,N,d].
// ---------------------------------------------------------------------------
__global__ __launch_bounds__(256) void k_qgemm(
    const float* __restrict__ x, const float* __restrict__ Wq,
    const float* __restrict__ bq, __hip_bfloat16* __restrict__ Qb)
{
    __shared__ float As[16][68];
    __shared__ float Bs[16][68];
    const int tid = threadIdx.x;
    const int tx = tid & 15, ty = tid >> 4;
    const int n0 = blockIdx.x * 64, j0 = blockIdx.y * 64, b = blockIdx.z;
    const int lk = tid >> 6, ln = tid & 63;
    const int lrow = tid >> 2, lq = tid & 3;
    float acc[4][4] = {};
    for (int c0 = 0; c0 < 512; c0 += 16) {
        __syncthreads();
        #pragma unroll
        for (int l = 0; l < 4; ++l) {
            int k = l * 4 + lk;
            As[k][ln] = x[((size_t)(b * C_DIM + c0 + k)) * NPIX + n0 + ln];
        }
        {
            float4 v = *(const float4*)&Wq[(size_t)(j0 + lrow) * 512 + c0 + lq * 4];
            Bs[lq*4+0][lrow] = v.x; Bs[lq*4+1][lrow] = v.y;
            Bs[lq*4+2][lrow] = v.z; Bs[lq*4+3][lrow] = v.w;
        }
        __syncthreads();
        #pragma unroll
        for (int k = 0; k < 16; ++k) {
            float4 av = *(const float4*)&As[k][ty * 4];
            float4 bv = *(const float4*)&Bs[k][tx * 4];
            float a[4] = {av.x, av.y, av.z, av.w};
            float bb[4] = {bv.x, bv.y, bv.z, bv.w};
            #pragma unroll
            for (int i = 0; i < 4; ++i)
                #pragma unroll
                for (int j = 0; j < 4; ++j)
                    acc[i][j] += a[i] * bb[j];
        }
    }
    const int h = j0 >> 6;
    #pragma unroll
    for (int i = 0; i < 4; ++i) {
        int n = n0 + ty * 4 + i;
        #pragma unroll
        for (int j = 0; j < 4; ++j) {
            int jg = j0 + tx * 4 + j; int d = jg & 63;
            Qb[(((size_t)(b * HEADS + h)) * N_SEQ + n) * HD + d] =
                __float2bfloat16(acc[i][j] + bq[jg]);
        }
    }
}

// ---------------------------------------------------------------------------
// Kernel E: attention. Block = (n-tile 64, h, b). No-max softmax (logits are
// small; exp stays in fp32 range): O = sum(e^s v) / sum(e^s).
// K chunk LDS buffer is reused for P=exp(S) (saves 17KB -> 52KB total LDS).
// ---------------------------------------------------------------------------
__global__ __launch_bounds__(256) void k_attn(
    const __hip_bfloat16* __restrict__ Qb, const __hip_bfloat16* __restrict__ Kb,
    const float* __restrict__ Vf, float* __restrict__ out)
{
    __shared__ float Qs[64][68];   // [d][i]
    __shared__ float KPs[64][68];  // K: [d][j]  then reused as P: [j][i]
    __shared__ float Vs[64][68];   // [j][d]
    const int tid = threadIdx.x;
    const int tx = tid & 15, ty = tid >> 4;
    const int n0 = blockIdx.x * 64, h = blockIdx.y, b = blockIdx.z;
    const size_t qbase = (((size_t)(b * HEADS + h)) * N_SEQ + n0) * HD;
    const size_t kvbase = ((size_t)(b * HEADS + h)) * M_TOT * HD;

    #pragma unroll
    for (int l = 0; l < 16; ++l) {
        int e = tid + l * 256;
        int i = e >> 6, d = e & 63;
        Qs[d][i] = __bfloat162float(Qb[qbase + (size_t)i * HD + d]);
    }
    float oacc[4][4] = {};
    float rs_acc[4] = {};
    __syncthreads();

    for (int jc0 = 0; jc0 < M_TOT; jc0 += 64) {
        // load K (into KPs) and V chunks
        #pragma unroll
        for (int l = 0; l < 16; ++l) {
            int e = tid + l * 256;
            int jj = e >> 6, d = e & 63;
            int jg = jc0 + jj;
            float kv_ = 0.f, vv = 0.f;
            if (jg < M_TOT) {
                kv_ = __bfloat162float(Kb[kvbase + (size_t)jg * HD + d]);
                vv  = Vf[kvbase + (size_t)jg * HD + d];
            }
            KPs[d][jj] = kv_;
            Vs[jj][d]  = vv;
        }
        __syncthreads();
        // S = Q K^T for this chunk
        float s[4][4] = {};
        #pragma unroll
        for (int k = 0; k < 64; ++k) {
            float4 av = *(const float4*)&Qs[k][ty * 4];
            float4 bv = *(const float4*)&KPs[k][tx * 4];
            float a[4] = {av.x, av.y, av.z, av.w};
            float bb[4] = {bv.x, bv.y, bv.z, bv.w};
            #pragma unroll
            for (int i = 0; i < 4; ++i)
                #pragma unroll
                for (int j = 0; j < 4; ++j)
                    s[i][j] += a[i] * bb[j];
        }
        __syncthreads();   // everyone done reading K before P overwrites it
        // P = exp(s * scale), masked; accumulate row sums via wave shuffle
        float psum[4];
        #pragma unroll
        for (int i = 0; i < 4; ++i) {
            psum[i] = 0.f;
            #pragma unroll
            for (int j = 0; j < 4; ++j) {
                int jg = jc0 + tx * 4 + j;
                float p = (jg < M_TOT) ? __expf(s[i][j] * SM_SCALE) : 0.f;
                KPs[tx * 4 + j][ty * 4 + i] = p;  // P[j][i]
                psum[i] += p;
            }
        }
        #pragma unroll
        for (int i = 0; i < 4; ++i) {
            float v = psum[i];
            v += __shfl_xor(v, 1); v += __shfl_xor(v, 2);
            v += __shfl_xor(v, 4); v += __shfl_xor(v, 8);
            rs_acc[i] += v;   // all 16 tx lanes hold the full row-chunk sum
        }
        __syncthreads();
        // O += P @ V
        #pragma unroll
        for (int j = 0; j < 64; ++j) {
            float4 av = *(const float4*)&KPs[j][ty * 4];  // P[j][i]
            float4 bv = *(const float4*)&Vs[j][tx * 4];
            float a[4] = {av.x, av.y, av.z, av.w};
            float bb[4] = {bv.x, bv.y, bv.z, bv.w};
            #pragma unroll
            for (int i = 0; i < 4; ++i)
                #pragma unroll
                for (int d = 0; d < 4; ++d)
                    oacc[i][d] += a[i] * bb[d];
        }
        __syncthreads();
    }
    #pragma unroll
    for (int i = 0; i < 4; ++i) {
        float inv = 1.f / rs_acc[i];
        int n = n0 + ty * 4 + i;
        float4 o;
        o.x = oacc[i][0] * inv; o.y = oacc[i][1] * inv;
        o.z = oacc[i][2] * inv; o.w = oacc[i][3] * inv;
        *(float4*)&out[((size_t)b * N_SEQ + n) * C_DIM + h * HD + tx * 4] = o;
    }
}

// ---------------------------------------------------------------------------
extern "C" void kernel_launch(void* const* d_in, const int* in_sizes, int n_in,
                              void* d_out, int out_size, void* d_ws, size_t ws_size,
                              hipStream_t stream) {
    const float* x     = (const float*)d_in[0];
    const float* Wq    = (const float*)d_in[1];
    const float* bq    = (const float*)d_in[2];
    const float* Wkv   = (const float*)d_in[3];
    const float* bkv   = (const float*)d_in[4];
    const float* w1a   = (const float*)d_in[5];
    const float* b1a   = (const float*)d_in[6];
    const float* w1b   = (const float*)d_in[7];
    const float* b1b   = (const float*)d_in[8];
    const float* w2    = (const float*)d_in[9];
    const float* b2    = (const float*)d_in[10];
    const float* w3    = (const float*)d_in[11];
    const float* b3    = (const float*)d_in[12];
    const float* gamma = (const float*)d_in[13];
    const float* beta  = (const float*)d_in[14];
    float* out = (float*)d_out;

    char* ws = (char*)d_ws;
    float*          l_pre = (float*)ws;                         // [B,C,M] 9,633,792 B
    float2*         stats = (float2*)(ws + 9633792);            //    37,632 B
    __hip_bfloat16* Qb    = (__hip_bfloat16*)(ws + 9671424);    // 25,690,112 B
    __hip_bfloat16* Kb    = (__hip_bfloat16*)(ws + 35361536);   //  4,816,896 B
    float*          Vf    = (float*)(ws + 40178432);            //  9,633,792 B (end ~47.5MB)

    k_branches<<<dim3(C_DIM, BATCH), 256, 0, stream>>>(
        x, w1a, b1a, w1b, b1b, w2, b2, w3, b3, l_pre);
    k_stats<<<dim3(10, BATCH), 256, 0, stream>>>(l_pre, stats);
    k_kvgemm<<<dim3(74, 16), 256, 0, stream>>>(
        l_pre, stats, Wkv, bkv, gamma, beta, Kb, Vf);
    k_qgemm<<<dim3(49, 8, BATCH), 256, 0, stream>>>(x, Wq, bq, Qb);
    k_attn<<<dim3(49, HEADS, BATCH), 256, 0, stream>>>(Qb, Kb, Vf, out);
}

// Round 2
// 499.978 us; speedup vs baseline: 8.9276x; 8.9276x over previous
//
#include <hip/hip_runtime.h>
#include <hip/hip_bf16.h>

#define BATCH   8
#define C_DIM   512
#define HWD     56
#define NPIX    3136   // 56*56
#define PW      14
#define PP      196    // 14*14
#define M_TOT   588    // 3*196
#define BM_ROWS 4704   // 8*588
#define HEADS   8
#define HD      64
#define N_SEQ   3136
#define SM_SCALE 0.125f

typedef __attribute__((ext_vector_type(8))) short bf16x8;
typedef __attribute__((ext_vector_type(4))) float f32x4;

__device__ __forceinline__ short f2bs(float f) {
    __hip_bfloat16 h = __float2bfloat16(f);
    return *reinterpret_cast<short*>(&h);
}
__device__ __forceinline__ float bs2f(short s) {
    __hip_bfloat16 h = *reinterpret_cast<__hip_bfloat16*>(&s);
    return __bfloat162float(h);
}

// ---------------------------------------------------------------------------
// Kernel A: the three depthwise branches. One block per (b,c) plane.
// Writes l_pre in [B, C, M] layout (coalesced 588-float runs per block).
// ---------------------------------------------------------------------------
__global__ __launch_bounds__(256) void k_branches(
    const float* __restrict__ x,
    const float* __restrict__ w1a, const float* __restrict__ b1a,
    const float* __restrict__ w1b, const float* __restrict__ b1b,
    const float* __restrict__ w2,  const float* __restrict__ b2,
    const float* __restrict__ w3,  const float* __restrict__ b3,
    float* __restrict__ l_pre)
{
    __shared__ float xs[NPIX];
    __shared__ float y1s[HWD * PW];   // 56x14 after (1,4) conv
    __shared__ float pools[PP];
    const int c = blockIdx.x, b = blockIdx.y, tid = threadIdx.x;
    const float* xp = x + ((size_t)(b * C_DIM + c)) * NPIX;
    for (int i = tid; i < NPIX / 4; i += 256)
        ((float4*)xs)[i] = ((const float4*)xp)[i];
    __syncthreads();

    const float wa0 = w1a[c*4+0], wa1 = w1a[c*4+1], wa2 = w1a[c*4+2], wa3 = w1a[c*4+3];
    const float ba = b1a[c];
    for (int i = tid; i < HWD * PW; i += 256) {
        int h = i / PW, w = i % PW;
        const float* r = xs + h * HWD + w * 4;
        float v = ba + r[0]*wa0 + r[1]*wa1 + r[2]*wa2 + r[3]*wa3;
        y1s[i] = fmaxf(v, 0.f);
    }
    if (tid < PP) {
        int h = tid / PW, w = tid % PW;
        float s = 0.f;
        #pragma unroll
        for (int r = 0; r < 4; ++r) {
            const float* rr = xs + (h*4 + r) * HWD + w * 4;
            s += rr[0] + rr[1] + rr[2] + rr[3];
        }
        pools[tid] = s * (1.f / 16.f);
    }
    __syncthreads();

    if (tid < PP) {
        int h = tid / PW, w = tid % PW;
        float* lp = l_pre + ((size_t)(b * C_DIM + c)) * M_TOT;
        float v1 = b1b[c];
        v1 += y1s[(h*4+0)*PW + w] * w1b[c*4+0];
        v1 += y1s[(h*4+1)*PW + w] * w1b[c*4+1];
        v1 += y1s[(h*4+2)*PW + w] * w1b[c*4+2];
        v1 += y1s[(h*4+3)*PW + w] * w1b[c*4+3];
        lp[tid] = fmaxf(v1, 0.f);
        float v2 = b2[c];
        #pragma unroll
        for (int r = 0; r < 4; ++r)
            #pragma unroll
            for (int s2 = 0; s2 < 4; ++s2)
                v2 += xs[(h*4+r)*HWD + w*4 + s2] * w2[c*16 + r*4 + s2];
        lp[PP + tid] = fmaxf(v2, 0.f);
        float v3 = b3[c];
        #pragma unroll
        for (int dh = -1; dh <= 1; ++dh)
            #pragma unroll
            for (int dw = -1; dw <= 1; ++dw) {
                int hh = h + dh, ww = w + dw;
                if (hh >= 0 && hh < PW && ww >= 0 && ww < PW)
                    v3 += pools[hh*PW + ww] * w3[c*9 + (dh+1)*3 + (dw+1)];
            }
        lp[2*PP + tid] = fmaxf(v3, 0.f);
    }
}

// ---------------------------------------------------------------------------
// Kernel B: LayerNorm stats over C for each (b,m). l_pre is [B,C,M].
// ---------------------------------------------------------------------------
__global__ __launch_bounds__(256) void k_stats(
    const float* __restrict__ l_pre, float2* __restrict__ stats)
{
    __shared__ float ssum[4][64];
    __shared__ float ssq[4][64];
    const int tid = threadIdx.x;
    const int ml = tid & 63, cg = tid >> 6;
    const int b = blockIdx.y;
    const int m = blockIdx.x * 64 + ml;
    float s = 0.f, q = 0.f;
    if (m < M_TOT) {
        const float* base = l_pre + ((size_t)b * C_DIM + cg * 128) * M_TOT + m;
        for (int c = 0; c < 128; ++c) {
            float v = base[(size_t)c * M_TOT];
            s += v; q += v * v;
        }
    }
    ssum[cg][ml] = s; ssq[cg][ml] = q;
    __syncthreads();
    if (tid < 64 && blockIdx.x * 64 + tid < M_TOT) {
        float ts = ssum[0][tid] + ssum[1][tid] + ssum[2][tid] + ssum[3][tid];
        float tq = ssq[0][tid] + ssq[1][tid] + ssq[2][tid] + ssq[3][tid];
        float mu = ts * (1.f / 512.f);
        float var = tq * (1.f / 512.f) - mu * mu;
        stats[(size_t)b * M_TOT + blockIdx.x * 64 + tid] =
            make_float2(mu, rsqrtf(var + 1e-5f));
    }
}

// ---------------------------------------------------------------------------
// Kernel C: kv = LN(l_) @ Wkv^T + bkv, LN fused into A-tile load.
// K written bf16 [B,h,M,d]; V written bf16 TRANSPOSED [B,h,d,M] for the
// attention PV B-operand (contiguous-j 16B frag loads).
// ---------------------------------------------------------------------------
__global__ __launch_bounds__(256) void k_kvgemm(
    const float* __restrict__ l_pre, const float2* __restrict__ stats,
    const float* __restrict__ Wkv, const float* __restrict__ bkv,
    const float* __restrict__ gamma, const float* __restrict__ beta,
    short* __restrict__ Kb, short* __restrict__ Vt)
{
    __shared__ float As[16][68];
    __shared__ float Bs[16][68];
    const int tid = threadIdx.x;
    const int tx = tid & 15, ty = tid >> 4;
    const int row0 = blockIdx.x * 64, col0 = blockIdx.y * 64;
    const int lk = tid >> 6, ln = tid & 63;
    const int grow = row0 + ln;
    const bool rv = (grow < BM_ROWS);
    int b_r = 0, m_r = 0; float mu = 0.f, rstd = 0.f;
    if (rv) {
        b_r = grow / M_TOT; m_r = grow - b_r * M_TOT;
        float2 st = stats[grow];
        mu = st.x; rstd = st.y;
    }
    const int lrow = tid >> 2, lq = tid & 3;
    float acc[4][4] = {};
    for (int c0 = 0; c0 < 512; c0 += 16) {
        __syncthreads();
        #pragma unroll
        for (int l = 0; l < 4; ++l) {
            int k = l * 4 + lk;
            float v = 0.f;
            if (rv) {
                float raw = l_pre[((size_t)(b_r * C_DIM + c0 + k)) * M_TOT + m_r];
                v = (raw - mu) * rstd * gamma[c0 + k] + beta[c0 + k];
            }
            As[k][ln] = v;
        }
        {
            float4 v = *(const float4*)&Wkv[(size_t)(col0 + lrow) * 512 + c0 + lq * 4];
            Bs[lq*4+0][lrow] = v.x; Bs[lq*4+1][lrow] = v.y;
            Bs[lq*4+2][lrow] = v.z; Bs[lq*4+3][lrow] = v.w;
        }
        __syncthreads();
        #pragma unroll
        for (int k = 0; k < 16; ++k) {
            float4 av = *(const float4*)&As[k][ty * 4];
            float4 bv = *(const float4*)&Bs[k][tx * 4];
            float a[4] = {av.x, av.y, av.z, av.w};
            float bb[4] = {bv.x, bv.y, bv.z, bv.w};
            #pragma unroll
            for (int i = 0; i < 4; ++i)
                #pragma unroll
                for (int j = 0; j < 4; ++j)
                    acc[i][j] += a[i] * bb[j];
        }
    }
    #pragma unroll
    for (int i = 0; i < 4; ++i) {
        int r = row0 + ty * 4 + i;
        if (r >= BM_ROWS) break;
        int bb_ = r / M_TOT, m = r - bb_ * M_TOT;
        #pragma unroll
        for (int j = 0; j < 4; ++j) {
            int jg = col0 + tx * 4 + j;
            float val = acc[i][j] + bkv[jg];
            if (jg < 512) {
                int h = jg >> 6, d = jg & 63;
                Kb[(((size_t)(bb_ * HEADS + h)) * M_TOT + m) * HD + d] = f2bs(val);
            } else {
                int jj = jg - 512; int h = jj >> 6, d = jj & 63;
                Vt[(((size_t)(bb_ * HEADS + h)) * HD + d) * M_TOT + m] = f2bs(val);
            }
        }
    }
}

// ---------------------------------------------------------------------------
// Kernel D: q = x_layer @ Wq^T + bq. Q written bf16 [B,h,N,d].
// ---------------------------------------------------------------------------
__global__ __launch_bounds__(256) void k_qgemm(
    const float* __restrict__ x, const float* __restrict__ Wq,
    const float* __restrict__ bq, short* __restrict__ Qb)
{
    __shared__ float As[16][68];
    __shared__ float Bs[16][68];
    const int tid = threadIdx.x;
    const int tx = tid & 15, ty = tid >> 4;
    const int n0 = blockIdx.x * 64, j0 = blockIdx.y * 64, b = blockIdx.z;
    const int lk = tid >> 6, ln = tid & 63;
    const int lrow = tid >> 2, lq = tid & 3;
    float acc[4][4] = {};
    for (int c0 = 0; c0 < 512; c0 += 16) {
        __syncthreads();
        #pragma unroll
        for (int l = 0; l < 4; ++l) {
            int k = l * 4 + lk;
            As[k][ln] = x[((size_t)(b * C_DIM + c0 + k)) * NPIX + n0 + ln];
        }
        {
            float4 v = *(const float4*)&Wq[(size_t)(j0 + lrow) * 512 + c0 + lq * 4];
            Bs[lq*4+0][lrow] = v.x; Bs[lq*4+1][lrow] = v.y;
            Bs[lq*4+2][lrow] = v.z; Bs[lq*4+3][lrow] = v.w;
        }
        __syncthreads();
        #pragma unroll
        for (int k = 0; k < 16; ++k) {
            float4 av = *(const float4*)&As[k][ty * 4];
            float4 bv = *(const float4*)&Bs[k][tx * 4];
            float a[4] = {av.x, av.y, av.z, av.w};
            float bb[4] = {bv.x, bv.y, bv.z, bv.w};
            #pragma unroll
            for (int i = 0; i < 4; ++i)
                #pragma unroll
                for (int j = 0; j < 4; ++j)
                    acc[i][j] += a[i] * bb[j];
        }
    }
    const int h = j0 >> 6;
    #pragma unroll
    for (int i = 0; i < 4; ++i) {
        int n = n0 + ty * 4 + i;
        #pragma unroll
        for (int j = 0; j < 4; ++j) {
            int jg = j0 + tx * 4 + j; int d = jg & 63;
            Qb[(((size_t)(b * HEADS + h)) * N_SEQ + n) * HD + d] =
                f2bs(acc[i][j] + bq[jg]);
        }
    }
}

// ---------------------------------------------------------------------------
// Kernel E: MFMA attention. Block = (n-tile 64, h, b), 4 waves.
// Wave w owns Q-rows w*16..w*16+15. Per 64-wide K/V chunk:
//   S strip = Q.K^T via 16x16x32 bf16 MFMA (A=Q frag hoisted, B=K frag)
//   P = exp(S*scale) (no-max softmax; logits are small), bf16-rounded,
//       row-sums accumulate the ROUNDED p so normalization is exact.
//   P goes C-layout -> A-layout via wave-local LDS round-trip (no barrier).
//   O strip += P.V via MFMA (B = V^T frag from Vs[d][j]).
// LDS rows padded to 72 bf16 (144 B, 16B-aligned) for clean b128 access.
// ---------------------------------------------------------------------------
__global__ __launch_bounds__(256) void k_attn(
    const short* __restrict__ Qb, const short* __restrict__ Kb,
    const short* __restrict__ Vt, float* __restrict__ out)
{
    __shared__ __align__(16) short Qs[64][72];
    __shared__ __align__(16) short Ks[64][72];
    __shared__ __align__(16) short Vs[64][72];   // Vs[d][j]
    __shared__ __align__(16) short Ps[64][72];   // P[i][j], wave-local strips
    const int tid = threadIdx.x;
    const int lane = tid & 63, w = tid >> 6;
    const int l15 = lane & 15, quad = lane >> 4;
    const int n0 = blockIdx.x * 64, h = blockIdx.y, b = blockIdx.z;
    const size_t bh = (size_t)(b * HEADS + h);
    const size_t qbase = (bh * N_SEQ + n0) * HD;
    const size_t kbase = bh * M_TOT * HD;
    const size_t vbase = bh * (size_t)HD * M_TOT;

    // stage Q (64 rows x 64 bf16; 512 x 16B ops over 256 threads)
    #pragma unroll
    for (int it = 0; it < 2; ++it) {
        int idx = tid + it * 256;
        int row = idx >> 3, seg = idx & 7;
        *(float4*)&Qs[row][seg * 8] =
            *(const float4*)(Qb + qbase + (size_t)row * HD + seg * 8);
    }

    f32x4 oacc[4] = {};       // [d_t] tiles, 4 rows each
    float rs[4] = {0.f, 0.f, 0.f, 0.f};

    __syncthreads();
    // Q frags: invariant across chunks — load once
    bf16x8 qf[2];
    #pragma unroll
    for (int ks = 0; ks < 2; ++ks)
        qf[ks] = *(const bf16x8*)&Qs[w * 16 + l15][ks * 32 + quad * 8];

    for (int jc0 = 0; jc0 < M_TOT; jc0 += 64) {
        // ---- stage K chunk (rows j, cols d) and V chunk (rows d, cols j)
        if (jc0 + 64 <= M_TOT) {
            #pragma unroll
            for (int it = 0; it < 2; ++it) {
                int idx = tid + it * 256;
                int row = idx >> 3, seg = idx & 7;
                *(float4*)&Ks[row][seg * 8] =
                    *(const float4*)(Kb + kbase + (size_t)(jc0 + row) * HD + seg * 8);
                *(float4*)&Vs[row][seg * 8] =
                    *(const float4*)(Vt + vbase + (size_t)row * M_TOT + jc0 + seg * 8);
            }
        } else {
            #pragma unroll
            for (int it = 0; it < 2; ++it) {
                int idx = tid + it * 256;
                int row = idx >> 3, seg = idx & 7;
                int jg = jc0 + row;
                if (jg < M_TOT) {
                    *(float4*)&Ks[row][seg * 8] =
                        *(const float4*)(Kb + kbase + (size_t)jg * HD + seg * 8);
                } else {
                    float4 z = {0.f, 0.f, 0.f, 0.f};
                    *(float4*)&Ks[row][seg * 8] = z;
                }
                #pragma unroll
                for (int t2 = 0; t2 < 8; ++t2) {
                    int jj = jc0 + seg * 8 + t2;
                    Vs[row][seg * 8 + t2] = (jj < M_TOT)
                        ? Vt[vbase + (size_t)row * M_TOT + jj] : (short)0;
                }
            }
        }
        __syncthreads();

        // ---- S strip = Q.K^T (4 n-tiles x 2 k-steps)
        f32x4 sacc[4] = {};
        #pragma unroll
        for (int nt = 0; nt < 4; ++nt)
            #pragma unroll
            for (int ks = 0; ks < 2; ++ks) {
                bf16x8 kf = *(const bf16x8*)&Ks[nt * 16 + l15][ks * 32 + quad * 8];
                sacc[nt] = __builtin_amdgcn_mfma_f32_16x16x32_bf16(
                    qf[ks], kf, sacc[nt], 0, 0, 0);
            }

        // ---- softmax chunk: p = exp(s*scale), bf16-round, store to Ps,
        //      accumulate rounded row sums (butterfly over the 16 col-lanes)
        float psum[4] = {0.f, 0.f, 0.f, 0.f};
        #pragma unroll
        for (int nt = 0; nt < 4; ++nt) {
            int jg = jc0 + nt * 16 + l15;
            #pragma unroll
            for (int r = 0; r < 4; ++r) {
                float p = (jg < M_TOT) ? __expf(sacc[nt][r] * SM_SCALE) : 0.f;
                short pb = f2bs(p);
                Ps[w * 16 + quad * 4 + r][nt * 16 + l15] = pb;
                psum[r] += bs2f(pb);
            }
        }
        #pragma unroll
        for (int r = 0; r < 4; ++r) {
            float v = psum[r];
            v += __shfl_xor(v, 1); v += __shfl_xor(v, 2);
            v += __shfl_xor(v, 4); v += __shfl_xor(v, 8);
            rs[r] += v;
        }

        // ---- O strip += P.V (wave-local Ps: compiler inserts lgkmcnt wait)
        bf16x8 pf[2];
        #pragma unroll
        for (int ks = 0; ks < 2; ++ks)
            pf[ks] = *(const bf16x8*)&Ps[w * 16 + l15][ks * 32 + quad * 8];
        #pragma unroll
        for (int dt = 0; dt < 4; ++dt)
            #pragma unroll
            for (int ks = 0; ks < 2; ++ks) {
                bf16x8 vf = *(const bf16x8*)&Vs[dt * 16 + l15][ks * 32 + quad * 8];
                oacc[dt] = __builtin_amdgcn_mfma_f32_16x16x32_bf16(
                    pf[ks], vf, oacc[dt], 0, 0, 0);
            }
        __syncthreads();   // all waves done with Ks/Vs before next staging
    }

    // ---- epilogue: normalize and write [B,N,C]
    #pragma unroll
    for (int r = 0; r < 4; ++r) {
        float inv = 1.f / rs[r];
        int n = n0 + w * 16 + quad * 4 + r;
        #pragma unroll
        for (int dt = 0; dt < 4; ++dt)
            out[((size_t)b * N_SEQ + n) * C_DIM + h * HD + dt * 16 + l15] =
                oacc[dt][r] * inv;
    }
}

// ---------------------------------------------------------------------------
extern "C" void kernel_launch(void* const* d_in, const int* in_sizes, int n_in,
                              void* d_out, int out_size, void* d_ws, size_t ws_size,
                              hipStream_t stream) {
    const float* x     = (const float*)d_in[0];
    const float* Wq    = (const float*)d_in[1];
    const float* bq    = (const float*)d_in[2];
    const float* Wkv   = (const float*)d_in[3];
    const float* bkv   = (const float*)d_in[4];
    const float* w1a   = (const float*)d_in[5];
    const float* b1a   = (const float*)d_in[6];
    const float* w1b   = (const float*)d_in[7];
    const float* b1b   = (const float*)d_in[8];
    const float* w2    = (const float*)d_in[9];
    const float* b2    = (const float*)d_in[10];
    const float* w3    = (const float*)d_in[11];
    const float* b3    = (const float*)d_in[12];
    const float* gamma = (const float*)d_in[13];
    const float* beta  = (const float*)d_in[14];
    float* out = (float*)d_out;

    char* ws = (char*)d_ws;
    float*  l_pre = (float*)ws;                    // [B,C,M]   9,633,792 B
    float2* stats = (float2*)(ws + 9633792);       //              37,632 B
    short*  Qb    = (short*)(ws + 9671424);        // [B,h,N,d] 25,690,112 B
    short*  Kb    = (short*)(ws + 35361536);       // [B,h,M,d]  4,816,896 B
    short*  Vt    = (short*)(ws + 40178432);       // [B,h,d,M]  4,816,896 B

    k_branches<<<dim3(C_DIM, BATCH), 256, 0, stream>>>(
        x, w1a, b1a, w1b, b1b, w2, b2, w3, b3, l_pre);
    k_stats<<<dim3(10, BATCH), 256, 0, stream>>>(l_pre, stats);
    k_kvgemm<<<dim3(74, 16), 256, 0, stream>>>(
        l_pre, stats, Wkv, bkv, gamma, beta, Kb, Vt);
    k_qgemm<<<dim3(49, 8, BATCH), 256, 0, stream>>>(x, Wq, bq, Qb);
    k_attn<<<dim3(49, HEADS, BATCH), 256, 0, stream>>>(Qb, Kb, Vt, out);
}

// Round 3
// 293.284 us; speedup vs baseline: 15.2194x; 1.7048x over previous
//
#include <hip/hip_runtime.h>
#include <hip/hip_bf16.h>

#define BATCH   8
#define C_DIM   512
#define HWD     56
#define NPIX    3136   // 56*56
#define PW      14
#define PP      196    // 14*14
#define M_TOT   588    // 3*196
#define BM_ROWS 4704   // 8*588
#define BM_PAD  4736   // padded to 37*128
#define HEADS   8
#define HD      64
#define N_SEQ   3136
#define SM_SCALE 0.125f

typedef __attribute__((ext_vector_type(8))) short bf16x8;
typedef __attribute__((ext_vector_type(4))) float f32x4;

__device__ __forceinline__ short f2bs(float f) {
    __hip_bfloat16 h = __float2bfloat16(f);
    return *reinterpret_cast<short*>(&h);
}
__device__ __forceinline__ float bs2f(short s) {
    __hip_bfloat16 h = *reinterpret_cast<__hip_bfloat16*>(&s);
    return __bfloat162float(h);
}

// async 16B global->LDS copy. lds ptr must be wave-uniform; lane fills
// lds_base + lane*16 (m97 pattern).
__device__ __forceinline__ void gl_lds16(const void* g, void* l) {
    __builtin_amdgcn_global_load_lds(
        (const __attribute__((address_space(1))) void*)g,
        (__attribute__((address_space(3))) void*)l, 16, 0, 0);
}

// ---------------------------------------------------------------------------
// Kernel A: the three depthwise branches. One block per (b,c) plane.
// Writes l_pre in [B, C, M] layout.
// ---------------------------------------------------------------------------
__global__ __launch_bounds__(256) void k_branches(
    const float* __restrict__ x,
    const float* __restrict__ w1a, const float* __restrict__ b1a,
    const float* __restrict__ w1b, const float* __restrict__ b1b,
    const float* __restrict__ w2,  const float* __restrict__ b2,
    const float* __restrict__ w3,  const float* __restrict__ b3,
    float* __restrict__ l_pre)
{
    __shared__ float xs[NPIX];
    __shared__ float y1s[HWD * PW];   // 56x14 after (1,4) conv
    __shared__ float pools[PP];
    const int c = blockIdx.x, b = blockIdx.y, tid = threadIdx.x;
    const float* xp = x + ((size_t)(b * C_DIM + c)) * NPIX;
    for (int i = tid; i < NPIX / 4; i += 256)
        ((float4*)xs)[i] = ((const float4*)xp)[i];
    __syncthreads();

    const float wa0 = w1a[c*4+0], wa1 = w1a[c*4+1], wa2 = w1a[c*4+2], wa3 = w1a[c*4+3];
    const float ba = b1a[c];
    for (int i = tid; i < HWD * PW; i += 256) {
        int h = i / PW, w = i % PW;
        const float* r = xs + h * HWD + w * 4;
        float v = ba + r[0]*wa0 + r[1]*wa1 + r[2]*wa2 + r[3]*wa3;
        y1s[i] = fmaxf(v, 0.f);
    }
    if (tid < PP) {
        int h = tid / PW, w = tid % PW;
        float s = 0.f;
        #pragma unroll
        for (int r = 0; r < 4; ++r) {
            const float* rr = xs + (h*4 + r) * HWD + w * 4;
            s += rr[0] + rr[1] + rr[2] + rr[3];
        }
        pools[tid] = s * (1.f / 16.f);
    }
    __syncthreads();

    if (tid < PP) {
        int h = tid / PW, w = tid % PW;
        float* lp = l_pre + ((size_t)(b * C_DIM + c)) * M_TOT;
        float v1 = b1b[c];
        v1 += y1s[(h*4+0)*PW + w] * w1b[c*4+0];
        v1 += y1s[(h*4+1)*PW + w] * w1b[c*4+1];
        v1 += y1s[(h*4+2)*PW + w] * w1b[c*4+2];
        v1 += y1s[(h*4+3)*PW + w] * w1b[c*4+3];
        lp[tid] = fmaxf(v1, 0.f);
        float v2 = b2[c];
        #pragma unroll
        for (int r = 0; r < 4; ++r)
            #pragma unroll
            for (int s2 = 0; s2 < 4; ++s2)
                v2 += xs[(h*4+r)*HWD + w*4 + s2] * w2[c*16 + r*4 + s2];
        lp[PP + tid] = fmaxf(v2, 0.f);
        float v3 = b3[c];
        #pragma unroll
        for (int dh = -1; dh <= 1; ++dh)
            #pragma unroll
            for (int dw = -1; dw <= 1; ++dw) {
                int hh = h + dh, ww = w + dw;
                if (hh >= 0 && hh < PW && ww >= 0 && ww < PW)
                    v3 += pools[hh*PW + ww] * w3[c*9 + (dh+1)*3 + (dw+1)];
            }
        lp[2*PP + tid] = fmaxf(v3, 0.f);
    }
}

// ---------------------------------------------------------------------------
// Kernel B: LayerNorm stats over C for each (b,m). l_pre is [B,C,M].
// ---------------------------------------------------------------------------
__global__ __launch_bounds__(256) void k_stats(
    const float* __restrict__ l_pre, float2* __restrict__ stats)
{
    __shared__ float ssum[4][64];
    __shared__ float ssq[4][64];
    const int tid = threadIdx.x;
    const int ml = tid & 63, cg = tid >> 6;
    const int b = blockIdx.y;
    const int m = blockIdx.x * 64 + ml;
    float s = 0.f, q = 0.f;
    if (m < M_TOT) {
        const float* base = l_pre + ((size_t)b * C_DIM + cg * 128) * M_TOT + m;
        for (int c = 0; c < 128; ++c) {
            float v = base[(size_t)c * M_TOT];
            s += v; q += v * v;
        }
    }
    ssum[cg][ml] = s; ssq[cg][ml] = q;
    __syncthreads();
    if (tid < 64 && blockIdx.x * 64 + tid < M_TOT) {
        float ts = ssum[0][tid] + ssum[1][tid] + ssum[2][tid] + ssum[3][tid];
        float tq = ssq[0][tid] + ssq[1][tid] + ssq[2][tid] + ssq[3][tid];
        float mu = ts * (1.f / 512.f);
        float var = tq * (1.f / 512.f) - mu * mu;
        stats[(size_t)b * M_TOT + blockIdx.x * 64 + tid] =
            make_float2(mu, rsqrtf(var + 1e-5f));
    }
}

// ---------------------------------------------------------------------------
// Kernel W: weights fp32 -> bf16 (layout preserved, row-major [out,512]).
// ---------------------------------------------------------------------------
__global__ __launch_bounds__(256) void k_wconv(
    const float* __restrict__ Wq, const float* __restrict__ Wkv,
    short* __restrict__ Wqb, short* __restrict__ Wkvb)
{
    int i = (blockIdx.x * 256 + threadIdx.x) * 4;
    if (i < 262144) {
        float4 v = *(const float4*)(Wq + i);
        short o[4] = {f2bs(v.x), f2bs(v.y), f2bs(v.z), f2bs(v.w)};
        *(short4*)(Wqb + i) = *(short4*)o;
    } else {
        int j = i - 262144;
        float4 v = *(const float4*)(Wkv + j);
        short o[4] = {f2bs(v.x), f2bs(v.y), f2bs(v.z), f2bs(v.w)};
        *(short4*)(Wkvb + j) = *(short4*)o;
    }
}

// ---------------------------------------------------------------------------
// Kernel X: x [B,C,N] fp32 -> Xb [B*N, C] bf16 (transpose + convert).
// ---------------------------------------------------------------------------
__global__ __launch_bounds__(256) void k_xpose(
    const float* __restrict__ x, short* __restrict__ Xb)
{
    __shared__ float sx[64][68];   // [c][n], 272B rows (16B aligned)
    const int tid = threadIdx.x;
    const int n0 = blockIdx.x * 64, c0 = blockIdx.y * 64, b = blockIdx.z;
    #pragma unroll
    for (int it = 0; it < 4; ++it) {
        int idx = tid + it * 256;
        int cr = idx >> 4, n4 = (idx & 15) * 4;
        float4 v = *(const float4*)(x + ((size_t)(b * C_DIM + c0 + cr)) * NPIX + n0 + n4);
        *(float4*)&sx[cr][n4] = v;
    }
    __syncthreads();
    #pragma unroll
    for (int p = 0; p < 2; ++p) {
        int idx = tid + p * 256;
        int nr = idx >> 3, cg = (idx & 7) * 8;
        short ov[8];
        #pragma unroll
        for (int e = 0; e < 8; ++e) ov[e] = f2bs(sx[cg + e][nr]);
        *(float4*)&Xb[((size_t)(b * NPIX + n0 + nr)) * C_DIM + c0 + cg] = *(float4*)ov;
    }
}

// ---------------------------------------------------------------------------
// Kernel L: LN(l_pre) transposed -> Lb [BM_PAD, C] bf16.
// Rows b*588+m for m<588; pad rows 4704..4735 left untouched (masked later).
// ---------------------------------------------------------------------------
__global__ __launch_bounds__(256) void k_lnt(
    const float* __restrict__ l_pre, const float2* __restrict__ stats,
    const float* __restrict__ gamma, const float* __restrict__ beta,
    short* __restrict__ Lb)
{
    __shared__ float sx[64][68];   // [c][m]
    const int tid = threadIdx.x;
    const int m0 = blockIdx.x * 64, c0 = blockIdx.y * 64, b = blockIdx.z;
    #pragma unroll
    for (int it = 0; it < 4; ++it) {
        int idx = tid + it * 256;
        int cr = idx >> 4, m4 = (idx & 15) * 4;
        float4 v = {0.f, 0.f, 0.f, 0.f};
        if (m0 + m4 < M_TOT)   // M_TOT%4==0 so float4 never straddles
            v = *(const float4*)(l_pre + ((size_t)(b * C_DIM + c0 + cr)) * M_TOT + m0 + m4);
        *(float4*)&sx[cr][m4] = v;
    }
    __syncthreads();
    #pragma unroll
    for (int p = 0; p < 2; ++p) {
        int idx = tid + p * 256;
        int mr = idx >> 3, cg = (idx & 7) * 8;
        int m = m0 + mr;
        float mu = 0.f, rstd = 0.f;
        if (m < M_TOT) {
            float2 st = stats[(size_t)b * M_TOT + m];
            mu = st.x; rstd = st.y;
        }
        short ov[8];
        #pragma unroll
        for (int e = 0; e < 8; ++e) {
            int c = c0 + cg + e;
            ov[e] = f2bs((sx[cg + e][mr] - mu) * rstd * gamma[c] + beta[c]);
        }
        if (m < M_TOT)
            *(float4*)&Lb[((size_t)(b * M_TOT + m)) * C_DIM + c0 + cg] = *(float4*)ov;
    }
}

// ---------------------------------------------------------------------------
// Kernel G: MFMA GEMM, 128x128 tile, BK=64, global_load_lds staging.
// D[row][col] = sum_c A[row][c] * Bw[col][c] + bias[col], both bf16 [.,512].
// MODE 0: rows = B*N, cols 512 -> Qb [B,h,N,d]
// MODE 1: rows = B*M (padded), cols 1024 -> Kb [B,h,M,d] / Vt [B,h,d,M]
// ---------------------------------------------------------------------------
template<int MODE>
__global__ __launch_bounds__(256) void k_gemm(
    const short* __restrict__ A, const short* __restrict__ Bw,
    const float* __restrict__ bias,
    short* __restrict__ Out0, short* __restrict__ Out1)
{
    __shared__ short As[128 * 64];
    __shared__ short Bs[128 * 64];
    const int tid = threadIdx.x;
    const int lane = tid & 63, w = tid >> 6;
    const int l15 = lane & 15, quad = lane >> 4;
    const int wr = w & 1, wc = w >> 1;
    const int row0 = blockIdx.x * 128, col0 = blockIdx.y * 128;
    const int lr8 = lane >> 3, lc8 = (lane & 7) * 8;

    f32x4 acc[4][4] = {};

    for (int c0 = 0; c0 < 512; c0 += 64) {
        __syncthreads();
        #pragma unroll
        for (int it = 0; it < 4; ++it) {
            int r = w * 32 + it * 8;     // wave-uniform LDS base row
            gl_lds16(A  + (size_t)(row0 + r + lr8) * 512 + c0 + lc8, &As[r * 64]);
            gl_lds16(Bw + (size_t)(col0 + r + lr8) * 512 + c0 + lc8, &Bs[r * 64]);
        }
        __syncthreads();
        #pragma unroll
        for (int ks = 0; ks < 2; ++ks) {
            bf16x8 af[4], bf[4];
            #pragma unroll
            for (int t = 0; t < 4; ++t) {
                af[t] = *(const bf16x8*)&As[(wr*64 + t*16 + l15)*64 + ks*32 + quad*8];
                bf[t] = *(const bf16x8*)&Bs[(wc*64 + t*16 + l15)*64 + ks*32 + quad*8];
            }
            #pragma unroll
            for (int nt = 0; nt < 4; ++nt)
                #pragma unroll
                for (int mt = 0; mt < 4; ++mt)
                    acc[nt][mt] = __builtin_amdgcn_mfma_f32_16x16x32_bf16(
                        af[nt], bf[mt], acc[nt][mt], 0, 0, 0);
        }
    }

    #pragma unroll
    for (int nt = 0; nt < 4; ++nt) {
        int row_t = row0 + wr * 64 + nt * 16 + quad * 4;
        #pragma unroll
        for (int mt = 0; mt < 4; ++mt) {
            int col = col0 + wc * 64 + mt * 16 + l15;
            float bv = bias[col];
            #pragma unroll
            for (int r = 0; r < 4; ++r) {
                int row_g = row_t + r;
                float v = acc[nt][mt][r] + bv;
                if (MODE == 0) {
                    int b = row_g / N_SEQ;
                    int n = row_g - b * N_SEQ;
                    int h = col >> 6, d = col & 63;
                    Out0[(((size_t)(b * HEADS + h)) * N_SEQ + n) * HD + d] = f2bs(v);
                } else {
                    if (row_g < BM_ROWS) {
                        int b = row_g / M_TOT;
                        int m = row_g - b * M_TOT;
                        if (col < 512) {
                            int h = col >> 6, d = col & 63;
                            Out0[(((size_t)(b * HEADS + h)) * M_TOT + m) * HD + d] = f2bs(v);
                        } else {
                            int jj = col - 512, h = jj >> 6, d = jj & 63;
                            Out1[(((size_t)(b * HEADS + h)) * HD + d) * M_TOT + m] = f2bs(v);
                        }
                    }
                }
            }
        }
    }
}

// ---------------------------------------------------------------------------
// Kernel E: MFMA attention (unchanged from R2).
// ---------------------------------------------------------------------------
__global__ __launch_bounds__(256) void k_attn(
    const short* __restrict__ Qb, const short* __restrict__ Kb,
    const short* __restrict__ Vt, float* __restrict__ out)
{
    __shared__ __align__(16) short Qs[64][72];
    __shared__ __align__(16) short Ks[64][72];
    __shared__ __align__(16) short Vs[64][72];   // Vs[d][j]
    __shared__ __align__(16) short Ps[64][72];   // P[i][j], wave-local strips
    const int tid = threadIdx.x;
    const int lane = tid & 63, w = tid >> 6;
    const int l15 = lane & 15, quad = lane >> 4;
    const int n0 = blockIdx.x * 64, h = blockIdx.y, b = blockIdx.z;
    const size_t bh = (size_t)(b * HEADS + h);
    const size_t qbase = (bh * N_SEQ + n0) * HD;
    const size_t kbase = bh * M_TOT * HD;
    const size_t vbase = bh * (size_t)HD * M_TOT;

    #pragma unroll
    for (int it = 0; it < 2; ++it) {
        int idx = tid + it * 256;
        int row = idx >> 3, seg = idx & 7;
        *(float4*)&Qs[row][seg * 8] =
            *(const float4*)(Qb + qbase + (size_t)row * HD + seg * 8);
    }

    f32x4 oacc[4] = {};
    float rs[4] = {0.f, 0.f, 0.f, 0.f};

    __syncthreads();
    bf16x8 qf[2];
    #pragma unroll
    for (int ks = 0; ks < 2; ++ks)
        qf[ks] = *(const bf16x8*)&Qs[w * 16 + l15][ks * 32 + quad * 8];

    for (int jc0 = 0; jc0 < M_TOT; jc0 += 64) {
        if (jc0 + 64 <= M_TOT) {
            #pragma unroll
            for (int it = 0; it < 2; ++it) {
                int idx = tid + it * 256;
                int row = idx >> 3, seg = idx & 7;
                *(float4*)&Ks[row][seg * 8] =
                    *(const float4*)(Kb + kbase + (size_t)(jc0 + row) * HD + seg * 8);
                *(float4*)&Vs[row][seg * 8] =
                    *(const float4*)(Vt + vbase + (size_t)row * M_TOT + jc0 + seg * 8);
            }
        } else {
            #pragma unroll
            for (int it = 0; it < 2; ++it) {
                int idx = tid + it * 256;
                int row = idx >> 3, seg = idx & 7;
                int jg = jc0 + row;
                if (jg < M_TOT) {
                    *(float4*)&Ks[row][seg * 8] =
                        *(const float4*)(Kb + kbase + (size_t)jg * HD + seg * 8);
                } else {
                    float4 z = {0.f, 0.f, 0.f, 0.f};
                    *(float4*)&Ks[row][seg * 8] = z;
                }
                #pragma unroll
                for (int t2 = 0; t2 < 8; ++t2) {
                    int jj = jc0 + seg * 8 + t2;
                    Vs[row][seg * 8 + t2] = (jj < M_TOT)
                        ? Vt[vbase + (size_t)row * M_TOT + jj] : (short)0;
                }
            }
        }
        __syncthreads();

        f32x4 sacc[4] = {};
        #pragma unroll
        for (int nt = 0; nt < 4; ++nt)
            #pragma unroll
            for (int ks = 0; ks < 2; ++ks) {
                bf16x8 kf = *(const bf16x8*)&Ks[nt * 16 + l15][ks * 32 + quad * 8];
                sacc[nt] = __builtin_amdgcn_mfma_f32_16x16x32_bf16(
                    qf[ks], kf, sacc[nt], 0, 0, 0);
            }

        float psum[4] = {0.f, 0.f, 0.f, 0.f};
        #pragma unroll
        for (int nt = 0; nt < 4; ++nt) {
            int jg = jc0 + nt * 16 + l15;
            #pragma unroll
            for (int r = 0; r < 4; ++r) {
                float p = (jg < M_TOT) ? __expf(sacc[nt][r] * SM_SCALE) : 0.f;
                short pb = f2bs(p);
                Ps[w * 16 + quad * 4 + r][nt * 16 + l15] = pb;
                psum[r] += bs2f(pb);
            }
        }
        #pragma unroll
        for (int r = 0; r < 4; ++r) {
            float v = psum[r];
            v += __shfl_xor(v, 1); v += __shfl_xor(v, 2);
            v += __shfl_xor(v, 4); v += __shfl_xor(v, 8);
            rs[r] += v;
        }

        bf16x8 pf[2];
        #pragma unroll
        for (int ks = 0; ks < 2; ++ks)
            pf[ks] = *(const bf16x8*)&Ps[w * 16 + l15][ks * 32 + quad * 8];
        #pragma unroll
        for (int dt = 0; dt < 4; ++dt)
            #pragma unroll
            for (int ks = 0; ks < 2; ++ks) {
                bf16x8 vf = *(const bf16x8*)&Vs[dt * 16 + l15][ks * 32 + quad * 8];
                oacc[dt] = __builtin_amdgcn_mfma_f32_16x16x32_bf16(
                    pf[ks], vf, oacc[dt], 0, 0, 0);
            }
        __syncthreads();
    }

    #pragma unroll
    for (int r = 0; r < 4; ++r) {
        float inv = 1.f / rs[r];
        int n = n0 + w * 16 + quad * 4 + r;
        #pragma unroll
        for (int dt = 0; dt < 4; ++dt)
            out[((size_t)b * N_SEQ + n) * C_DIM + h * HD + dt * 16 + l15] =
                oacc[dt][r] * inv;
    }
}

// ---------------------------------------------------------------------------
extern "C" void kernel_launch(void* const* d_in, const int* in_sizes, int n_in,
                              void* d_out, int out_size, void* d_ws, size_t ws_size,
                              hipStream_t stream) {
    const float* x     = (const float*)d_in[0];
    const float* Wq    = (const float*)d_in[1];
    const float* bq    = (const float*)d_in[2];
    const float* Wkv   = (const float*)d_in[3];
    const float* bkv   = (const float*)d_in[4];
    const float* w1a   = (const float*)d_in[5];
    const float* b1a   = (const float*)d_in[6];
    const float* w1b   = (const float*)d_in[7];
    const float* b1b   = (const float*)d_in[8];
    const float* w2    = (const float*)d_in[9];
    const float* b2    = (const float*)d_in[10];
    const float* w3    = (const float*)d_in[11];
    const float* b3    = (const float*)d_in[12];
    const float* gamma = (const float*)d_in[13];
    const float* beta  = (const float*)d_in[14];
    float* out = (float*)d_out;

    // Workspace layout. R0 (offset 0, 25.69MB) is time-aliased:
    //   phase 1: Xb [25088,512] bf16   (k_xpose -> k_gemm<0>)
    //   phase 2: l_pre + stats + Lb    (k_branches onward)
    char* ws = (char*)d_ws;
    short*  Xb    = (short*)ws;                    // 25,690,112 B
    float*  l_pre = (float*)ws;                    //  9,633,792 B (aliases Xb)
    float2* stats = (float2*)(ws + 9633792);       //     37,632 B
    short*  Lb    = (short*)(ws + 9671424);        //  4,849,664 B ([4736,512])
    short*  Wqb   = (short*)(ws + 25690112);       //    524,288 B
    short*  Wkvb  = (short*)(ws + 26214400);       //  1,048,576 B
    short*  Kb    = (short*)(ws + 27262976);       //  4,816,896 B [B,h,M,d]
    short*  Vt    = (short*)(ws + 32079872);       //  4,816,896 B [B,h,d,M]
    short*  Qb    = (short*)(ws + 36896768);       // 25,690,112 B [B,h,N,d]

    k_wconv<<<768, 256, 0, stream>>>(Wq, Wkv, Wqb, Wkvb);
    k_xpose<<<dim3(49, 8, BATCH), 256, 0, stream>>>(x, Xb);
    k_gemm<0><<<dim3(196, 4), 256, 0, stream>>>(Xb, Wqb, bq, Qb, nullptr);
    // Xb dead; R0 becomes l_pre/stats/Lb
    k_branches<<<dim3(C_DIM, BATCH), 256, 0, stream>>>(
        x, w1a, b1a, w1b, b1b, w2, b2, w3, b3, l_pre);
    k_stats<<<dim3(10, BATCH), 256, 0, stream>>>(l_pre, stats);
    k_lnt<<<dim3(10, 8, BATCH), 256, 0, stream>>>(l_pre, stats, gamma, beta, Lb);
    k_gemm<1><<<dim3(37, 8), 256, 0, stream>>>(Lb, Wkvb, bkv, Kb, Vt);
    k_attn<<<dim3(49, HEADS, BATCH), 256, 0, stream>>>(Qb, Kb, Vt, out);
}